// Round 11
// baseline (56.956 us; speedup 1.0000x reference)
//
#include <hip/hip_runtime.h>
#include <string.h>

#define AA (-0.75f)

__device__ __forceinline__ float k1f(float x) {
    return ((AA + 2.0f) * x - (AA + 3.0f)) * x * x + 1.0f;
}
__device__ __forceinline__ float k2f(float x) {
    return ((AA * x - 5.0f * AA) * x + 8.0f * AA) * x - 4.0f * AA;
}

__device__ __forceinline__ int reflect_clip(int idx, int size) {
    int span = size - 1;
    int i = idx < 0 ? -idx : idx;
    i = i % (2 * span);
    if (i > span) i = 2 * span - i;
    return i;
}

// LDS bank swizzle: logical element a -> a ^ ((a>>5)&31). Bijective per row.
__device__ __forceinline__ int swz(int a) { return a ^ ((a >> 5) & 31); }

typedef float f32x4 __attribute__((ext_vector_type(4)));

// Inline-asm load: volatile -> program-order issue, results tracked only by
// OUR waitcnts below (compiler does not count asm loads).
#define GLOAD4(dst, ptr)                                                     \
    asm volatile("global_load_dwordx4 %0, %1, off"                           \
                 : "=v"(dst) : "v"(ptr))

// Separable bicubic, one block per (b,h), 256 threads.
// vs R10: counted vmcnt (T4) instead of a full vmcnt(0) drain. Combine is
// split into 4 stages, each waiting only for its own channel-group
// (vmcnt 12/8/4/0) so combine VALU + LDS writes overlap the younger loads'
// flight. rule #18: sched_barrier(0) after each asm waitcnt so p-reg uses
// cannot hoist above it.
__global__ __launch_bounds__(256, 4)
void pds11_kernel(const float* __restrict__ x,
                  const float* __restrict__ rate,
                  const float* __restrict__ center,
                  float* __restrict__ out)
{
    constexpr int C = 8, H = 512, W = 512, HW = H * W;

    // XCD-chunked remap (8192 % 8 == 0 -> bijective).
    const int orig = blockIdx.x;
    const int id = (orig & 7) * 1024 + (orig >> 3);
    const int b = id >> 9;
    const int h = id & (H - 1);

    const float r  = rate[b];
    const float cx = center[2 * b + 0];
    const float cy = center[2 * b + 1];
    const float inv_r = 1.0f / r;
    const int t = threadIdx.x;

    // ---- y taps (block-uniform, short chain) ----
    const float gy = 0.00390625f * (float)h - 1.0f;
    const float Gy = (gy - cy) * inv_r + cy;
    const float iy = (Gy + 1.0f) * 0.5f * 511.0f;
    const float y0 = floorf(iy);
    const float ty = iy - y0;
    const int   y0i = (int)y0;
    const float wy0 = k2f(ty + 1.0f);
    const float wy1 = k1f(ty);
    const float wy2 = k1f(1.0f - ty);
    const float wy3 = k2f(2.0f - ty);
    const int ro0 = reflect_clip(y0i - 1, H) * W;
    const int ro1 = reflect_clip(y0i    , H) * W;
    const int ro2 = reflect_clip(y0i + 1, H) * W;
    const int ro3 = reflect_clip(y0i + 2, H) * W;

    // ---- 16-deep load burst (asm, program order = group0..group3) ----
    const float* imgb = x + (size_t)b * C * HW;
    const int cc4 = (t & 127) << 2;           // 16B-aligned group in row
    const int ch0 = (t >> 7);                 // 0 or 1
    const float* base0 = imgb + (size_t)(ch0 + 0) * HW + cc4;
    const float* base1 = imgb + (size_t)(ch0 + 2) * HW + cc4;
    const float* base2 = imgb + (size_t)(ch0 + 4) * HW + cc4;
    const float* base3 = imgb + (size_t)(ch0 + 6) * HW + cc4;

    f32x4 p00, p01, p02, p03, p10, p11, p12, p13;
    f32x4 p20, p21, p22, p23, p30, p31, p32, p33;
    GLOAD4(p00, base0 + ro0);
    GLOAD4(p01, base0 + ro1);
    GLOAD4(p02, base0 + ro2);
    GLOAD4(p03, base0 + ro3);
    GLOAD4(p10, base1 + ro0);
    GLOAD4(p11, base1 + ro1);
    GLOAD4(p12, base1 + ro2);
    GLOAD4(p13, base1 + ro3);
    GLOAD4(p20, base2 + ro0);
    GLOAD4(p21, base2 + ro1);
    GLOAD4(p22, base2 + ro2);
    GLOAD4(p23, base2 + ro3);
    GLOAD4(p30, base3 + ro0);
    GLOAD4(p31, base3 + ro1);
    GLOAD4(p32, base3 + ro2);
    GLOAD4(p33, base3 + ro3);

    // ---- x taps for cols 2t, 2t+1 (independent VALU, under load flight) ----
    int   sA0, sA1, sA2, sA3, sB0, sB1, sB2, sB3;
    float wxA0, wxA1, wxA2, wxA3, wxB0, wxB1, wxB2, wxB3;
    {
        const int w = 2 * t;
        const float gx = 0.00390625f * (float)w - 1.0f;
        const float Gx = (gx - cx) * inv_r + cx;
        const float ix = (Gx + 1.0f) * 0.5f * 511.0f;
        const float x0 = floorf(ix);
        const float tx = ix - x0;
        const int x0i = (int)x0;
        wxA0 = k2f(tx + 1.0f); wxA1 = k1f(tx);
        wxA2 = k1f(1.0f - tx); wxA3 = k2f(2.0f - tx);
        sA0 = swz(reflect_clip(x0i - 1, W)); sA1 = swz(reflect_clip(x0i,     W));
        sA2 = swz(reflect_clip(x0i + 1, W)); sA3 = swz(reflect_clip(x0i + 2, W));
    }
    {
        const int w = 2 * t + 1;
        const float gx = 0.00390625f * (float)w - 1.0f;
        const float Gx = (gx - cx) * inv_r + cx;
        const float ix = (Gx + 1.0f) * 0.5f * 511.0f;
        const float x0 = floorf(ix);
        const float tx = ix - x0;
        const int x0i = (int)x0;
        wxB0 = k2f(tx + 1.0f); wxB1 = k1f(tx);
        wxB2 = k1f(1.0f - tx); wxB3 = k2f(2.0f - tx);
        sB0 = swz(reflect_clip(x0i - 1, W)); sB1 = swz(reflect_clip(x0i,     W));
        sB2 = swz(reflect_clip(x0i + 1, W)); sB3 = swz(reflect_clip(x0i + 2, W));
    }

    __shared__ float tmp[C][W];   // 16 KiB, swizzled rows

    // ---- staged vertical combine, counted vmcnt per channel-group ----
    const int v    = (cc4 >> 5) & 31;
    const int base = cc4 ^ (v & ~3);
    const int p    = v & 3;
    const bool q1 = (p & 1) != 0;
    const bool q2 = (p & 2) != 0;
#define COMB1(cc, a0, a1, a2, a3)                                          \
    {                                                                      \
        float e0 = wy0 * a0.x + wy1 * a1.x + wy2 * a2.x + wy3 * a3.x;      \
        float e1 = wy0 * a0.y + wy1 * a1.y + wy2 * a2.y + wy3 * a3.y;      \
        float e2 = wy0 * a0.z + wy1 * a1.z + wy2 * a2.z + wy3 * a3.z;      \
        float e3 = wy0 * a0.w + wy1 * a1.w + wy2 * a2.w + wy3 * a3.w;      \
        float t0 = q1 ? e1 : e0;                                           \
        float t1 = q1 ? e0 : e1;                                           \
        float t2 = q1 ? e3 : e2;                                           \
        float t3 = q1 ? e2 : e3;                                           \
        float u0 = q2 ? t2 : t0;                                           \
        float u1 = q2 ? t3 : t1;                                           \
        float u2 = q2 ? t0 : t2;                                           \
        float u3 = q2 ? t1 : t3;                                           \
        *(float4*)&tmp[cc][base] = make_float4(u0, u1, u2, u3);            \
    }
    asm volatile("s_waitcnt vmcnt(12)" ::: "memory");
    __builtin_amdgcn_sched_barrier(0);
    COMB1(ch0 + 0, p00, p01, p02, p03);

    asm volatile("s_waitcnt vmcnt(8)" ::: "memory");
    __builtin_amdgcn_sched_barrier(0);
    COMB1(ch0 + 2, p10, p11, p12, p13);

    asm volatile("s_waitcnt vmcnt(4)" ::: "memory");
    __builtin_amdgcn_sched_barrier(0);
    COMB1(ch0 + 4, p20, p21, p22, p23);

    asm volatile("s_waitcnt vmcnt(0)" ::: "memory");
    __builtin_amdgcn_sched_barrier(0);
    COMB1(ch0 + 6, p30, p31, p32, p33);
#undef COMB1

    __syncthreads();

    // ---- horizontal pass: 4 LDS taps per output, NT float2 stores ----
    float* obase = out + ((size_t)b * C * H + h) * W + 2 * t;
    #pragma unroll
    for (int c = 0; c < C; ++c) {
        const float* tr = tmp[c];
        const float s0 = wxA0 * tr[sA0] + wxA1 * tr[sA1]
                       + wxA2 * tr[sA2] + wxA3 * tr[sA3];
        const float s1 = wxB0 * tr[sB0] + wxB1 * tr[sB1]
                       + wxB2 * tr[sB2] + wxB3 * tr[sB3];
        float2 v2 = make_float2(s0, s1);
        double dv;
        memcpy(&dv, &v2, 8);
        __builtin_nontemporal_store(dv, (double*)(obase + (size_t)c * HW));
    }
}

extern "C" void kernel_launch(void* const* d_in, const int* in_sizes, int n_in,
                              void* d_out, int out_size, void* d_ws, size_t ws_size,
                              hipStream_t stream) {
    const float* x      = (const float*)d_in[0];
    const float* rate   = (const float*)d_in[1];
    const float* center = (const float*)d_in[2];
    float* out          = (float*)d_out;

    constexpr int B = 16, H = 512;
    dim3 grid(B * H);
    dim3 block(256);
    pds11_kernel<<<grid, block, 0, stream>>>(x, rate, center, out);
}